// Round 6
// baseline (341.185 us; speedup 1.0000x reference)
//
#include <hip/hip_runtime.h>

#define LSEQ 4096
#define DMODEL 1024
#define HTOT 16
#define NAR 8
#define DHEAD 64
#define QKVS 3072  // fused QKV row stride

typedef unsigned short u16;
typedef unsigned int u32;
typedef __attribute__((ext_vector_type(8))) short bf16x8;
typedef __attribute__((ext_vector_type(4))) short bf16x4;
typedef __attribute__((ext_vector_type(4))) float f32x4;
typedef __attribute__((ext_vector_type(4))) unsigned int u32x4;

typedef __attribute__((address_space(1))) void gvoid;
typedef __attribute__((address_space(3))) void lvoid;

__device__ __forceinline__ void cp16(const void* g, void* l) {
    // async global->LDS, 16B per lane; LDS dest = wave-uniform base + lane*16
    __builtin_amdgcn_global_load_lds((gvoid*)(void*)g, (lvoid*)l, 16, 0, 0);
}

// round-to-nearest-even fp32 -> bf16
__device__ __forceinline__ u16 f2bf(float f) {
    u32 x = __float_as_uint(f);
    return (u16)((x + 0x7fffu + ((x >> 16) & 1u)) >> 16);
}
// truncation-pack two fp32 -> packed bf16x2 (1 v_perm_b32)
__device__ __forceinline__ u32 packtr(float lo, float hi) {
    return __builtin_amdgcn_perm(__float_as_uint(hi), __float_as_uint(lo), 0x07060302u);
}

// ---------------------------------------------------------------------------
// Fused transpose of Wq/Wk/Wv: 1024x1024 fp32 -> bf16 (D = S^T), z selects.
// ---------------------------------------------------------------------------
__global__ __launch_bounds__(256) void transp_cvt3(
    const float* __restrict__ Wq, const float* __restrict__ Wk,
    const float* __restrict__ Wv, u16* __restrict__ D)
{
    __shared__ u16 T[64][72];
    const float* S = (blockIdx.z == 0) ? Wq : ((blockIdx.z == 1) ? Wk : Wv);
    u16* Dz = D + (size_t)blockIdx.z * 1024 * 1024;
    const int tid = threadIdx.x;
    const int bx = blockIdx.x, by = blockIdx.y;
#pragma unroll
    for (int i = 0; i < 4; ++i) {
        int id = tid + i * 256;
        int fr = id >> 4, fc = id & 15;
        float4 v = *(const float4*)(S + (size_t)(by * 64 + fr) * 1024 + bx * 64 + fc * 4);
        T[fc * 4 + 0][fr] = f2bf(v.x);
        T[fc * 4 + 1][fr] = f2bf(v.y);
        T[fc * 4 + 2][fr] = f2bf(v.z);
        T[fc * 4 + 3][fr] = f2bf(v.w);
    }
    __syncthreads();
#pragma unroll
    for (int i = 0; i < 2; ++i) {
        int id = tid + i * 256;
        int c = id >> 3, g = id & 7;
        *(uint4*)(Dz + (size_t)(bx * 64 + c) * 1024 + by * 64 + g * 8) = *(const uint4*)&T[c][g * 8];
    }
}

// single-matrix version for Wo
__global__ __launch_bounds__(256) void transp_cvt(
    const float* __restrict__ S, u16* __restrict__ D)
{
    __shared__ u16 T[64][72];
    const int tid = threadIdx.x;
    const int bx = blockIdx.x, by = blockIdx.y;
#pragma unroll
    for (int i = 0; i < 4; ++i) {
        int id = tid + i * 256;
        int fr = id >> 4, fc = id & 15;
        float4 v = *(const float4*)(S + (size_t)(by * 64 + fr) * 1024 + bx * 64 + fc * 4);
        T[fc * 4 + 0][fr] = f2bf(v.x);
        T[fc * 4 + 1][fr] = f2bf(v.y);
        T[fc * 4 + 2][fr] = f2bf(v.z);
        T[fc * 4 + 3][fr] = f2bf(v.w);
    }
    __syncthreads();
#pragma unroll
    for (int i = 0; i < 2; ++i) {
        int id = tid + i * 256;
        int c = id >> 3, g = id & 7;
        *(uint4*)(D + (size_t)(bx * 64 + c) * 1024 + by * 64 + g * 8) = *(const uint4*)&T[c][g * 8];
    }
}

// ---------------------------------------------------------------------------
// QKV = X @ [Wq|Wk|Wv] + FUSED RoPE epilogue. A fp32 (trunc-packed to bf16),
// Bt bf16 k-major, C bf16. 128x128 tile, BK=32, dbuf LDS, one barrier/K-step.
// ---------------------------------------------------------------------------
__global__ __launch_bounds__(256) void gemm_qkv(
    const float* __restrict__ A, const u16* __restrict__ Bt, u16* __restrict__ C)
{
    __shared__ u16 As[2][128][40];
    __shared__ u16 Bs[2][128][32];
    const int tid = threadIdx.x;
    const int lane = tid & 63, w = tid >> 6;
    const int col = lane & 15, quad = lane >> 4;
    const int bm = blockIdx.y << 7, bn = blockIdx.x << 7;
    const int wm = (w & 1) << 6, wn = (w >> 1) << 6;
    const int sr = lane >> 2, sc = (lane & 3) << 3;
    const int ar0 = tid >> 2, ag = (tid & 3) << 3;
    const f32x4 zero = {0.f, 0.f, 0.f, 0.f};
    f32x4 acc[4][4];
#pragma unroll
    for (int i = 0; i < 4; ++i)
#pragma unroll
        for (int j = 0; j < 4; ++j) acc[i][j] = zero;

    // prologue: stage k0=0 into buf 0
    {
#pragma unroll
        for (int i = 0; i < 2; ++i)
            cp16(Bt + (size_t)(bn + w * 32 + i * 16 + sr) * 1024 + sc, &Bs[0][w * 32 + i * 16][0]);
#pragma unroll
        for (int it = 0; it < 2; ++it) {
            const float* ap = A + (size_t)(bm + ar0 + it * 64) * 1024 + ag;
            float4 a0 = *(const float4*)ap;
            float4 a1 = *(const float4*)(ap + 4);
            uint4 pk;
            pk.x = packtr(a0.x, a0.y); pk.y = packtr(a0.z, a0.w);
            pk.z = packtr(a1.x, a1.y); pk.w = packtr(a1.z, a1.w);
            *(uint4*)&As[0][ar0 + it * 64][ag] = pk;
        }
    }

    for (int kc = 0; kc < 32; ++kc) {
        const int cur = kc & 1, nxt = cur ^ 1;
        __syncthreads();
        const bool pre = (kc + 1 < 32);
        float4 a0[2], a1[2];
        if (pre) {
            const int k1 = (kc + 1) * 32;
#pragma unroll
            for (int i = 0; i < 2; ++i)
                cp16(Bt + (size_t)(bn + w * 32 + i * 16 + sr) * 1024 + k1 + sc,
                     &Bs[nxt][w * 32 + i * 16][0]);
#pragma unroll
            for (int it = 0; it < 2; ++it) {
                const float* ap = A + (size_t)(bm + ar0 + it * 64) * 1024 + k1 + ag;
                a0[it] = *(const float4*)ap;
                a1[it] = *(const float4*)(ap + 4);
            }
        }
        bf16x8 af[4], bfr[4];
#pragma unroll
        for (int i = 0; i < 4; ++i) af[i] = *(const bf16x8*)&As[cur][wm + i * 16 + col][quad * 8];
#pragma unroll
        for (int j = 0; j < 4; ++j) bfr[j] = *(const bf16x8*)&Bs[cur][wn + j * 16 + col][quad * 8];
#pragma unroll
        for (int i = 0; i < 4; ++i)
#pragma unroll
            for (int j = 0; j < 4; ++j)
                acc[i][j] = __builtin_amdgcn_mfma_f32_16x16x32_bf16(af[i], bfr[j], acc[i][j], 0, 0, 0);
        if (pre) {
#pragma unroll
            for (int it = 0; it < 2; ++it) {
                uint4 pk;
                pk.x = packtr(a0[it].x, a0[it].y); pk.y = packtr(a0[it].z, a0[it].w);
                pk.z = packtr(a1[it].x, a1[it].y); pk.w = packtr(a1[it].z, a1[it].w);
                *(uint4*)&As[nxt][ar0 + it * 64][ag] = pk;
            }
        }
    }

    // fused RoPE epilogue (Q and K blocks only)
    if (blockIdx.x < 16) {
        const float scale = (blockIdx.x < 8) ? 0.18033688011112042f : 1.0f;  // Q: (1/8)*log2e
        const float inv0 = __expf((float)col * -0.2878231366242557f);         // irope = col
        const float inv1 = __expf((float)(16 + col) * -0.2878231366242557f);  // irope = 16+col
#pragma unroll
        for (int i = 0; i < 4; ++i)
#pragma unroll
            for (int r = 0; r < 4; ++r) {
                const float t = (float)(bm + wm + i * 16 + quad * 4 + r);
                float s0, c0, s1, c1;
                __sincosf(t * inv0, &s0, &c0);
                __sincosf(t * inv1, &s1, &c1);
                float a0 = acc[i][0][r], b0 = acc[i][2][r];
                acc[i][0][r] = (a0 * c0 - b0 * s0) * scale;
                acc[i][2][r] = (b0 * c0 + a0 * s0) * scale;
                float a1 = acc[i][1][r], b1 = acc[i][3][r];
                acc[i][1][r] = (a1 * c1 - b1 * s1) * scale;
                acc[i][3][r] = (b1 * c1 + a1 * s1) * scale;
            }
    }
#pragma unroll
    for (int i = 0; i < 4; ++i)
#pragma unroll
        for (int j = 0; j < 4; ++j)
#pragma unroll
            for (int r = 0; r < 4; ++r)
                C[(size_t)(bm + wm + i * 16 + quad * 4 + r) * QKVS + bn + wn + j * 16 + col] =
                    f2bf(acc[i][j][r]);
}

// ---------------------------------------------------------------------------
// out = AO @ Wot^T  (both bf16 k-major, C fp32). Double-buffered, one barrier
// per K-step, both operands via async global_load_lds.
// ---------------------------------------------------------------------------
__global__ __launch_bounds__(256) void gemm_out(
    const u16* __restrict__ A, const u16* __restrict__ Bt, float* __restrict__ C)
{
    __shared__ u16 As[2][128][32];
    __shared__ u16 Bs[2][128][32];
    const int tid = threadIdx.x;
    const int lane = tid & 63, w = tid >> 6;
    const int col = lane & 15, quad = lane >> 4;
    const int bm = blockIdx.y << 7, bn = blockIdx.x << 7;
    const int wm = (w & 1) << 6, wn = (w >> 1) << 6;
    const int sr = lane >> 2, sc = (lane & 3) << 3;
    const f32x4 zero = {0.f, 0.f, 0.f, 0.f};
    f32x4 acc[4][4];
#pragma unroll
    for (int i = 0; i < 4; ++i)
#pragma unroll
        for (int j = 0; j < 4; ++j) acc[i][j] = zero;

#pragma unroll
    for (int i = 0; i < 2; ++i) {
        const int r0 = w * 32 + i * 16;
        cp16(A  + (size_t)(bm + r0 + sr) * 1024 + sc, &As[0][r0][0]);
        cp16(Bt + (size_t)(bn + r0 + sr) * 1024 + sc, &Bs[0][r0][0]);
    }

    for (int kc = 0; kc < 32; ++kc) {
        const int cur = kc & 1, nxt = cur ^ 1;
        __syncthreads();
        if (kc + 1 < 32) {
            const int k1 = (kc + 1) * 32;
#pragma unroll
            for (int i = 0; i < 2; ++i) {
                const int r0 = w * 32 + i * 16;
                cp16(A  + (size_t)(bm + r0 + sr) * 1024 + k1 + sc, &As[nxt][r0][0]);
                cp16(Bt + (size_t)(bn + r0 + sr) * 1024 + k1 + sc, &Bs[nxt][r0][0]);
            }
        }
        bf16x8 af[4], bfr[4];
#pragma unroll
        for (int i = 0; i < 4; ++i) af[i] = *(const bf16x8*)&As[cur][wm + i * 16 + col][quad * 8];
#pragma unroll
        for (int j = 0; j < 4; ++j) bfr[j] = *(const bf16x8*)&Bs[cur][wn + j * 16 + col][quad * 8];
#pragma unroll
        for (int i = 0; i < 4; ++i)
#pragma unroll
            for (int j = 0; j < 4; ++j)
                acc[i][j] = __builtin_amdgcn_mfma_f32_16x16x32_bf16(af[i], bfr[j], acc[i][j], 0, 0, 0);
    }
#pragma unroll
    for (int i = 0; i < 4; ++i)
#pragma unroll
        for (int j = 0; j < 4; ++j)
#pragma unroll
            for (int r = 0; r < 4; ++r)
                C[(size_t)(bm + wm + i * 16 + quad * 4 + r) * 1024 + bn + wn + j * 16 + col] =
                    acc[i][j][r];
}

// zero the per-job merge flags (512 u32 in d_out tail)
__global__ __launch_bounds__(256) void zero_flags(u32* __restrict__ f)
{
    const int i = blockIdx.x * 256 + threadIdx.x;
    if (i < 512) f[i] = 0;
}

// ---------------------------------------------------------------------------
// MFMA flash attention v10 — v9 pipeline + 2-way KV-split for balance:
//  * r5 model: makespan = worst-CU wave-units x 6560cyc / (4 SIMD x N). With
//    512 blocks (2/CU, zero slack) pigeonhole forces a 64-unit CU (avg 48.5)
//    and N=2. Split every job into 2 KV-parts (<=17 units), 1024 blocks,
//    3 LDS-resident/CU -> dynamic backfill balances AND N->3.
//  * Merge (split jobs only): election flag +1 -> who. FIRST finisher writes
//    fp32 (O,l) partials to a d_out scratch slot, __threadfence (release,
//    L2 writeback), flag +4. SECOND spins for flag>=6 (both elections + data
//    ready), acquire-fences, reads partner, adds in regs, normalizes, writes
//    AO. No O-atomics, no extra passes; fp32-reorder-only numerics.
//  * Ks buffer parity now (ch-c0)&1 (causal part c0 can be odd).
//  * Per-chunk math unchanged (cperm Vt single-buf, K=32 PV, ks-outer S,
//    setprio). LDS 50176 + 4.
// ---------------------------------------------------------------------------
__global__ __launch_bounds__(256) void attn_mfma(
    const u16* __restrict__ QKV, u16* __restrict__ AO,
    float* __restrict__ OS, u32* __restrict__ flags)
{
    __shared__ u16 Ks[2][128][64];   // [key][dim], unpadded, XOR-swizzled 16B blocks
    __shared__ u16 Vt[64][136];      // [dim][cperm(key)] single-buffered + 8-u16 pad
    __shared__ int sflag;
    const int b = blockIdx.x;
    const int jid = b >> 1, p = b & 1;
    int h, qt;
    if (jid < 256) { h = 8 + (jid & 7); qt = jid >> 3; }           // diff
    else { const int i = jid - 256; h = i & 7; qt = 31 - (i >> 3); } // causal desc qt
    const bool causal = (h < NAR);
    int c0, c1;
    bool split;
    if (!causal) { split = true; c0 = p * 16; c1 = c0 + 16; }      // 16+16 chunks
    else {
        const int nch = qt + 1;
        split = (qt >= 15);
        if (!split) {
            if (p) return;                                         // empty part
            c0 = 0; c1 = nch;
        } else {
            const int h1 = (nch + 1) >> 1;                         // ceil(nch/2)
            c0 = p ? h1 : 0; c1 = p ? nch : h1;
        }
    }
    const int tid = threadIdx.x;
    const int w = tid >> 6, lane = tid & 63;
    const int col = lane & 15, quad = lane >> 4;
    const int qb = qt * 128;
    const int qr0 = qb + w * 32 + col;
    const int qr1 = qr0 + 16;
    // column-permuted position of key a=2*lane (a's pair b=a+1 sits at cva+1)
    const int cva = ((lane >> 1) & 3) * 32 + (lane >> 3) * 4 + (lane & 1) * 2;

    // hoisted Q B-frags (rope'd, pre-scaled by 0.125*log2e in gemm_qkv)
    bf16x8 qf[2][2];
#pragma unroll
    for (int s = 0; s < 2; ++s)
#pragma unroll
        for (int ks = 0; ks < 2; ++ks)
            qf[s][ks] = *(const bf16x8*)(QKV + (size_t)(qr0 + s * 16) * QKVS +
                                         h * DHEAD + ks * 32 + quad * 8);

    bf16x8 ones8;
#pragma unroll
    for (int i = 0; i < 8; ++i) ones8[i] = (short)0x3F80;

    const f32x4 zero = {0.f, 0.f, 0.f, 0.f};
    f32x4 O[2][5];  // [set][nd] O^T tiles (d = nd*16+quad*4+r, q = col); nd=4 = l
#pragma unroll
    for (int s = 0; s < 2; ++s)
#pragma unroll
        for (int nd = 0; nd < 5; ++nd) O[s][nd] = zero;

    const int krow = lane >> 3;
    const int kcb = (lane & 7) ^ krow;
    const u16* kbase = QKV + (size_t)krow * QKVS + 1024 + h * DHEAD + kcb * 8;
    const u16* vbase = QKV + (size_t)(lane * 2) * QKVS + 2048 + h * DHEAD + w * 16;

    u32x4 vA0, vA1, vB0, vB1;   // pending V(ch) regs for end-of-iter Vt write
    bf16x8 pf8[2][4];           // P(ch) frags: pf8[s][tp] = keys 32tp..32tp+31 (permuted)

#define VT_WRITE()                                                                                 \
    _Pragma("unroll")                                                                              \
    for (int j = 0; j < 4; ++j) {                                                                  \
        *(u32*)&Vt[w * 16 + 2 * j][cva]         = __builtin_amdgcn_perm(vB0[j], vA0[j], 0x05040100u); \
        *(u32*)&Vt[w * 16 + 2 * j + 1][cva]     = __builtin_amdgcn_perm(vB0[j], vA0[j], 0x07060302u); \
        *(u32*)&Vt[w * 16 + 8 + 2 * j][cva]     = __builtin_amdgcn_perm(vB1[j], vA1[j], 0x05040100u); \
        *(u32*)&Vt[w * 16 + 8 + 2 * j + 1][cva] = __builtin_amdgcn_perm(vB1[j], vA1[j], 0x07060302u); \
    }

// PV burst over Vt at K=32: tp-outer, l-row folded in -> acc reuse distance 10.
#define PV_STEP()                                                                                  \
    {                                                                                              \
        __builtin_amdgcn_s_setprio(1);                                                             \
        _Pragma("unroll")                                                                          \
        for (int tp = 0; tp < 4; ++tp) {                                                           \
            bf16x8 vv[4];                                                                          \
            _Pragma("unroll")                                                                      \
            for (int nd = 0; nd < 4; ++nd)                                                         \
                vv[nd] = *(const bf16x8*)&Vt[nd * 16 + col][quad * 32 + tp * 8];                   \
            _Pragma("unroll")                                                                      \
            for (int nd = 0; nd < 4; ++nd) {                                                       \
                O[0][nd] = __builtin_amdgcn_mfma_f32_16x16x32_bf16(vv[nd], pf8[0][tp], O[0][nd], 0, 0, 0); \
                O[1][nd] = __builtin_amdgcn_mfma_f32_16x16x32_bf16(vv[nd], pf8[1][tp], O[1][nd], 0, 0, 0); \
            }                                                                                      \
            O[0][4] = __builtin_amdgcn_mfma_f32_16x16x32_bf16(ones8, pf8[0][tp], O[0][4], 0, 0, 0); \
            O[1][4] = __builtin_amdgcn_mfma_f32_16x16x32_bf16(ones8, pf8[1][tp], O[1][4], 0, 0, 0); \
        }                                                                                          \
        __builtin_amdgcn_s_setprio(0);                                                             \
    }

// S(CH) + exp -> pf8. ks-outer: st[s][jj] reuse distance 8.
#define S_STEP(KBUF, CH)                                                                           \
    {                                                                                              \
        const bool mask = causal && ((CH) == qt);                                                  \
        _Pragma("unroll")                                                                          \
        for (int hf = 0; hf < 2; ++hf) {                                                           \
            f32x4 st[2][4];                                                                        \
            _Pragma("unroll")                                                                      \
            for (int s = 0; s < 2; ++s)                                                            \
                _Pragma("unroll")                                                                  \
                for (int jj = 0; jj < 4; ++jj) st[s][jj] = zero;                                   \
            __builtin_amdgcn_s_setprio(1);                                                         \
            _Pragma("unroll")                                                                      \
            for (int ks = 0; ks < 2; ++ks)                                                         \
                _Pragma("unroll")                                                                  \
                for (int jj = 0; jj < 4; ++jj) {                                                   \
                    bf16x8 kf = *(const bf16x8*)&Ks[KBUF][(hf * 4 + jj) * 16 + col]                \
                                                         [((ks * 4 + quad) ^ (col & 7)) * 8];      \
                    st[0][jj] = __builtin_amdgcn_mfma_f32_16x16x32_bf16(kf, qf[0][ks], st[0][jj], 0, 0, 0); \
                    st[1][jj] = __builtin_amdgcn_mfma_f32_16x16x32_bf16(kf, qf[1][ks], st[1][jj], 0, 0, 0); \
                }                                                                                  \
            __builtin_amdgcn_s_setprio(0);                                                         \
            if (mask) {                                                                            \
                _Pragma("unroll")                                                                  \
                for (int jj = 0; jj < 4; ++jj) {                                                   \
                    const int kk = (CH) * 128 + (hf * 4 + jj) * 16 + quad * 4;                     \
                    _Pragma("unroll")                                                              \
                    for (int r = 0; r < 4; ++r) {                                                  \
                        if (kk + r > qr0) st[0][jj][r] = -1e30f;                                   \
                        if (kk + r > qr1) st[1][jj][r] = -1e30f;                                   \
                    }                                                                              \
                }                                                                                  \
            }                                                                                      \
            _Pragma("unroll")                                                                      \
            for (int s = 0; s < 2; ++s)                                                            \
                _Pragma("unroll")                                                                  \
                for (int jj = 0; jj < 4; ++jj) {                                                   \
                    u32 plo = packtr(__builtin_amdgcn_exp2f(st[s][jj][0]),                         \
                                     __builtin_amdgcn_exp2f(st[s][jj][1]));                        \
                    u32 phi = packtr(__builtin_amdgcn_exp2f(st[s][jj][2]),                         \
                                     __builtin_amdgcn_exp2f(st[s][jj][3]));                        \
                    u32* pp = (u32*)&pf8[s][0] + (hf * 4 + jj) * 2;                                \
                    pp[0] = plo; pp[1] = phi;                                                      \
                }                                                                                  \
        }                                                                                          \
    }

    // ---- prologue: stage chunk c0 into Ks[0] ----
#pragma unroll
    for (int i = 0; i < 4; ++i)
        cp16(kbase + (size_t)(c0 * 128 + (i * 4 + w) * 8) * QKVS, &Ks[0][(i * 4 + w) * 8][0]);
    {
        const u16* vp = vbase + (size_t)c0 * 128 * QKVS;
        vA0 = *(u32x4*)(vp);
        vA1 = *(u32x4*)(vp + 8);
        vB0 = *(u32x4*)(vp + QKVS);
        vB1 = *(u32x4*)(vp + QKVS + 8);
    }
    __syncthreads();  // K(c0) in LDS, V(c0) in regs
    VT_WRITE();       // Vt <- V(c0)
    if (c1 - c0 > 1) {  // prefetch K(c0+1) into Ks[1]
#pragma unroll
        for (int i = 0; i < 4; ++i)
            cp16(kbase + (size_t)((c0 + 1) * 128 + (i * 4 + w) * 8) * QKVS, &Ks[1][(i * 4 + w) * 8][0]);
    }
    S_STEP(0, c0);    // pf8 = P(c0)

    // ---- main loop ----
    for (int ch = c0 + 1; ch < c1; ++ch) {
        const int rel = (ch - c0) & 1;
        __syncthreads();  // barrier_a: Ks[rel]=K(ch) drained; Vt=V(ch-1) visible
        if (ch + 1 < c1) {  // prefetch K(ch+1) into buffer S(ch) is NOT reading
            const size_t cc = (size_t)(ch + 1) * 128;
#pragma unroll
            for (int i = 0; i < 4; ++i)
                cp16(kbase + (cc + (i * 4 + w) * 8) * QKVS, &Ks[rel ^ 1][(i * 4 + w) * 8][0]);
        }
        {   // V(ch) regs for end-of-iter Vt write
            const u16* vp = vbase + (size_t)ch * 128 * QKVS;
            vA0 = *(u32x4*)(vp);
            vA1 = *(u32x4*)(vp + 8);
            vB0 = *(u32x4*)(vp + QKVS);
            vB1 = *(u32x4*)(vp + QKVS + 8);
        }
        PV_STEP();        // P(ch-1) x V(ch-1)
        S_STEP(rel, ch);  // -> pf8 = P(ch)
        __syncthreads();  // barrier_b: all PV reads done; loads above drained
        VT_WRITE();       // Vt <- V(ch)
    }

    // ---- tail: PV(c1-1) ----
    __syncthreads();
    PV_STEP();

    if (!split) {
        // direct epilogue: l in-lane (col=q); O^T rows d = nd*16+quad*4+r
#pragma unroll
        for (int s = 0; s < 2; ++s) {
            const float inv = 1.f / O[s][4][0];
            const int qrow = qr0 + s * 16;
#pragma unroll
            for (int nd = 0; nd < 4; ++nd) {
                ushort4 ov;
                ov.x = f2bf(O[s][nd][0] * inv);
                ov.y = f2bf(O[s][nd][1] * inv);
                ov.z = f2bf(O[s][nd][2] * inv);
                ov.w = f2bf(O[s][nd][3] * inv);
                *(ushort4*)(AO + (size_t)qrow * 1024 + h * DHEAD + nd * 16 + quad * 4) = ov;
            }
        }
        return;
    }

    // ---- split-job merge: slot [128][68] fp32 per jid (jid < 392) ----
    const int ql = w * 32 + col;
    float* slot = OS + (size_t)jid * 128 * 68;
    if (tid == 0) sflag = (int)atomicAdd(&flags[jid], 1u);
    __syncthreads();
    const int who = sflag & 3;
    if (who == 0) {
        // FIRST finisher: publish fp32 partials, release, signal data-ready
#pragma unroll
        for (int s = 0; s < 2; ++s) {
            float* row = slot + (size_t)(ql + s * 16) * 68;
#pragma unroll
            for (int nd = 0; nd < 4; ++nd)
                *(f32x4*)(row + nd * 16 + quad * 4) = O[s][nd];
            if (quad == 0) row[64] = O[s][4][0];
        }
        __threadfence();   // release: make stores device-visible (L2 writeback)
        __syncthreads();   // all waves published
        if (tid == 0) atomicAdd(&flags[jid], 4u);   // flag: 2 elections + 4 = 6
        return;
    }
    // SECOND finisher: wait for partner's data, merge, output
    if (tid == 0) {
        while (__hip_atomic_load(&flags[jid], __ATOMIC_RELAXED, __HIP_MEMORY_SCOPE_AGENT) < 6u)
            __builtin_amdgcn_s_sleep(2);
    }
    __syncthreads();
    __threadfence();       // acquire: invalidate caches before partner reads
#pragma unroll
    for (int s = 0; s < 2; ++s) {
        const float* row = slot + (size_t)(ql + s * 16) * 68;
        const float l = O[s][4][0] + row[64];
        const float inv = 1.f / l;
        const int qrow = qr0 + s * 16;
#pragma unroll
        for (int nd = 0; nd < 4; ++nd) {
            f32x4 pv = *(const f32x4*)(row + nd * 16 + quad * 4);
            ushort4 ov;
            ov.x = f2bf((O[s][nd][0] + pv[0]) * inv);
            ov.y = f2bf((O[s][nd][1] + pv[1]) * inv);
            ov.z = f2bf((O[s][nd][2] + pv[2]) * inv);
            ov.w = f2bf((O[s][nd][3] + pv[3]) * inv);
            *(ushort4*)(AO + (size_t)qrow * 1024 + h * DHEAD + nd * 16 + quad * 4) = ov;
        }
    }
#undef VT_WRITE
#undef PV_STEP
#undef S_STEP
}

// ---------------------------------------------------------------------------
extern "C" void kernel_launch(void* const* d_in, const int* in_sizes, int n_in,
                              void* d_out, int out_size, void* d_ws, size_t ws_size,
                              hipStream_t stream)
{
    const float* X  = (const float*)d_in[0];
    const float* Wq = (const float*)d_in[1];
    const float* Wk = (const float*)d_in[2];
    const float* Wv = (const float*)d_in[3];
    const float* Wo = (const float*)d_in[4];
    float* out = (float*)d_out;

    // ws (u16 units), liveness overlays:
    //   [0 .. 4M):   Wqkvt [3072][1024] (dead after gemm_qkv) -> AOb [4096][1024]
    //   [4M .. 16M): QKV [4096][3072] (dead after attn) -> Wot [1024][1024]
    // d_out (16 MB fp32) during attn: OS scratch 392 slots x [128][68] fp32
    //   (13.65 MB) + flags (512 u32) at float offset 4,000,000; fully
    //   overwritten by gemm_out afterwards.
    u16* Wt  = (u16*)d_ws;
    u16* AOb = (u16*)d_ws;
    u16* QKV = (u16*)d_ws + (size_t)4 * 1024 * 1024;
    u16* Wot = QKV;
    float* OS = out;
    u32* flags = (u32*)(out + 4000000);

    zero_flags<<<2, 256, 0, stream>>>(flags);
    transp_cvt3<<<dim3(16, 16, 3), 256, 0, stream>>>(Wq, Wk, Wv, Wt);
    gemm_qkv<<<dim3(24, 32), 256, 0, stream>>>(X, Wt, QKV);   // rope fused in epilogue
    attn_mfma<<<1024, 256, 0, stream>>>(QKV, AOb, OS, flags);
    transp_cvt<<<dim3(16, 16), 256, 0, stream>>>(Wo, Wot);    // QKV dead now
    gemm_out<<<dim3(8, 32), 256, 0, stream>>>(AOb, Wot, out); // overwrites OS scratch
}

// Round 7
// 243.010 us; speedup vs baseline: 1.4040x; 1.4040x over previous
//
#include <hip/hip_runtime.h>

#define LSEQ 4096
#define DMODEL 1024
#define HTOT 16
#define NAR 8
#define DHEAD 64
#define QKVS 3072  // fused QKV row stride

typedef unsigned short u16;
typedef unsigned int u32;
typedef __attribute__((ext_vector_type(8))) short bf16x8;
typedef __attribute__((ext_vector_type(4))) short bf16x4;
typedef __attribute__((ext_vector_type(4))) float f32x4;
typedef __attribute__((ext_vector_type(4))) unsigned int u32x4;

typedef __attribute__((address_space(1))) void gvoid;
typedef __attribute__((address_space(3))) void lvoid;

__device__ __forceinline__ void cp16(const void* g, void* l) {
    // async global->LDS, 16B per lane; LDS dest = wave-uniform base + lane*16
    __builtin_amdgcn_global_load_lds((gvoid*)(void*)g, (lvoid*)l, 16, 0, 0);
}

// round-to-nearest-even fp32 -> bf16
__device__ __forceinline__ u16 f2bf(float f) {
    u32 x = __float_as_uint(f);
    return (u16)((x + 0x7fffu + ((x >> 16) & 1u)) >> 16);
}
// truncation-pack two fp32 -> packed bf16x2 (1 v_perm_b32)
__device__ __forceinline__ u32 packtr(float lo, float hi) {
    return __builtin_amdgcn_perm(__float_as_uint(hi), __float_as_uint(lo), 0x07060302u);
}

// ---------------------------------------------------------------------------
// X (fp32) -> Xb (bf16, truncated) once, so gemm_qkv needs no per-K-step
// VALU repack. Bit-identical to the old in-loop packtr path.
// ---------------------------------------------------------------------------
__global__ __launch_bounds__(256) void xcast(const float* __restrict__ X, u16* __restrict__ Xb)
{
    const size_t i = (size_t)(blockIdx.x * 256 + threadIdx.x) * 8;
    float4 a0 = *(const float4*)(X + i);
    float4 a1 = *(const float4*)(X + i + 4);
    uint4 pk;
    pk.x = packtr(a0.x, a0.y); pk.y = packtr(a0.z, a0.w);
    pk.z = packtr(a1.x, a1.y); pk.w = packtr(a1.z, a1.w);
    *(uint4*)(Xb + i) = pk;
}

// ---------------------------------------------------------------------------
// Fused transpose of Wq/Wk/Wv: 1024x1024 fp32 -> bf16 (D = S^T), z selects.
// ---------------------------------------------------------------------------
__global__ __launch_bounds__(256) void transp_cvt3(
    const float* __restrict__ Wq, const float* __restrict__ Wk,
    const float* __restrict__ Wv, u16* __restrict__ D)
{
    __shared__ u16 T[64][72];
    const float* S = (blockIdx.z == 0) ? Wq : ((blockIdx.z == 1) ? Wk : Wv);
    u16* Dz = D + (size_t)blockIdx.z * 1024 * 1024;
    const int tid = threadIdx.x;
    const int bx = blockIdx.x, by = blockIdx.y;
#pragma unroll
    for (int i = 0; i < 4; ++i) {
        int id = tid + i * 256;
        int fr = id >> 4, fc = id & 15;
        float4 v = *(const float4*)(S + (size_t)(by * 64 + fr) * 1024 + bx * 64 + fc * 4);
        T[fc * 4 + 0][fr] = f2bf(v.x);
        T[fc * 4 + 1][fr] = f2bf(v.y);
        T[fc * 4 + 2][fr] = f2bf(v.z);
        T[fc * 4 + 3][fr] = f2bf(v.w);
    }
    __syncthreads();
#pragma unroll
    for (int i = 0; i < 2; ++i) {
        int id = tid + i * 256;
        int c = id >> 3, g = id & 7;
        *(uint4*)(Dz + (size_t)(bx * 64 + c) * 1024 + by * 64 + g * 8) = *(const uint4*)&T[c][g * 8];
    }
}

// single-matrix version for Wo
__global__ __launch_bounds__(256) void transp_cvt(
    const float* __restrict__ S, u16* __restrict__ D)
{
    __shared__ u16 T[64][72];
    const int tid = threadIdx.x;
    const int bx = blockIdx.x, by = blockIdx.y;
#pragma unroll
    for (int i = 0; i < 4; ++i) {
        int id = tid + i * 256;
        int fr = id >> 4, fc = id & 15;
        float4 v = *(const float4*)(S + (size_t)(by * 64 + fr) * 1024 + bx * 64 + fc * 4);
        T[fc * 4 + 0][fr] = f2bf(v.x);
        T[fc * 4 + 1][fr] = f2bf(v.y);
        T[fc * 4 + 2][fr] = f2bf(v.z);
        T[fc * 4 + 3][fr] = f2bf(v.w);
    }
    __syncthreads();
#pragma unroll
    for (int i = 0; i < 2; ++i) {
        int id = tid + i * 256;
        int c = id >> 3, g = id & 7;
        *(uint4*)(D + (size_t)(bx * 64 + c) * 1024 + by * 64 + g * 8) = *(const uint4*)&T[c][g * 8];
    }
}

// ---------------------------------------------------------------------------
// QKV = Xb @ [Wq|Wk|Wv]^T(k-major) + FUSED RoPE epilogue. Both operands bf16
// via cp16 (pure m97 structure — the fp32 A-repack VALU path is gone).
// 128x128 tile, BK=32, dbuf LDS, one barrier/K-step.
// Epilogue: blocks bx<8 = Q (rope + 0.125*log2e scale), bx<16 = K (rope).
// ---------------------------------------------------------------------------
__global__ __launch_bounds__(256) void gemm_qkv(
    const u16* __restrict__ A, const u16* __restrict__ Bt, u16* __restrict__ C)
{
    __shared__ u16 As[2][128][32];
    __shared__ u16 Bs[2][128][32];
    const int tid = threadIdx.x;
    const int lane = tid & 63, w = tid >> 6;
    const int col = lane & 15, quad = lane >> 4;
    const int bm = blockIdx.y << 7, bn = blockIdx.x << 7;
    const int wm = (w & 1) << 6, wn = (w >> 1) << 6;
    const int sr = lane >> 2, sc = (lane & 3) << 3;
    const f32x4 zero = {0.f, 0.f, 0.f, 0.f};
    f32x4 acc[4][4];
#pragma unroll
    for (int i = 0; i < 4; ++i)
#pragma unroll
        for (int j = 0; j < 4; ++j) acc[i][j] = zero;

#pragma unroll
    for (int i = 0; i < 2; ++i) {
        const int r0 = w * 32 + i * 16;
        cp16(A  + (size_t)(bm + r0 + sr) * 1024 + sc, &As[0][r0][0]);
        cp16(Bt + (size_t)(bn + r0 + sr) * 1024 + sc, &Bs[0][r0][0]);
    }

    for (int kc = 0; kc < 32; ++kc) {
        const int cur = kc & 1, nxt = cur ^ 1;
        __syncthreads();
        if (kc + 1 < 32) {
            const int k1 = (kc + 1) * 32;
#pragma unroll
            for (int i = 0; i < 2; ++i) {
                const int r0 = w * 32 + i * 16;
                cp16(A  + (size_t)(bm + r0 + sr) * 1024 + k1 + sc, &As[nxt][r0][0]);
                cp16(Bt + (size_t)(bn + r0 + sr) * 1024 + k1 + sc, &Bs[nxt][r0][0]);
            }
        }
        bf16x8 af[4], bfr[4];
#pragma unroll
        for (int i = 0; i < 4; ++i) af[i] = *(const bf16x8*)&As[cur][wm + i * 16 + col][quad * 8];
#pragma unroll
        for (int j = 0; j < 4; ++j) bfr[j] = *(const bf16x8*)&Bs[cur][wn + j * 16 + col][quad * 8];
#pragma unroll
        for (int i = 0; i < 4; ++i)
#pragma unroll
            for (int j = 0; j < 4; ++j)
                acc[i][j] = __builtin_amdgcn_mfma_f32_16x16x32_bf16(af[i], bfr[j], acc[i][j], 0, 0, 0);
    }

    // fused RoPE epilogue (Q and K blocks only)
    if (blockIdx.x < 16) {
        const float scale = (blockIdx.x < 8) ? 0.18033688011112042f : 1.0f;  // Q: (1/8)*log2e
        const float inv0 = __expf((float)col * -0.2878231366242557f);         // irope = col
        const float inv1 = __expf((float)(16 + col) * -0.2878231366242557f);  // irope = 16+col
#pragma unroll
        for (int i = 0; i < 4; ++i)
#pragma unroll
            for (int r = 0; r < 4; ++r) {
                const float t = (float)(bm + wm + i * 16 + quad * 4 + r);
                float s0, c0, s1, c1;
                __sincosf(t * inv0, &s0, &c0);
                __sincosf(t * inv1, &s1, &c1);
                float a0 = acc[i][0][r], b0 = acc[i][2][r];
                acc[i][0][r] = (a0 * c0 - b0 * s0) * scale;
                acc[i][2][r] = (b0 * c0 + a0 * s0) * scale;
                float a1 = acc[i][1][r], b1 = acc[i][3][r];
                acc[i][1][r] = (a1 * c1 - b1 * s1) * scale;
                acc[i][3][r] = (b1 * c1 + a1 * s1) * scale;
            }
    }
#pragma unroll
    for (int i = 0; i < 4; ++i)
#pragma unroll
        for (int j = 0; j < 4; ++j)
#pragma unroll
            for (int r = 0; r < 4; ++r)
                C[(size_t)(bm + wm + i * 16 + quad * 4 + r) * QKVS + bn + wn + j * 16 + col] =
                    f2bf(acc[i][j][r]);
}

// ---------------------------------------------------------------------------
// out = AO @ Wot^T (both bf16 k-major, C fp32). Retiled 128(M)x64(N):
// grid 16x32 = 512 blocks (was 256 = 1/CU latency-exposed) -> 2 blocks/CU.
// Waves 2x2 covering 64(M)x32(N) each; acc[4][2]; LDS 24 KB.
// ---------------------------------------------------------------------------
__global__ __launch_bounds__(256) void gemm_out(
    const u16* __restrict__ A, const u16* __restrict__ Bt, float* __restrict__ C)
{
    __shared__ u16 As[2][128][32];
    __shared__ u16 Bs[2][64][32];
    const int tid = threadIdx.x;
    const int lane = tid & 63, w = tid >> 6;
    const int col = lane & 15, quad = lane >> 4;
    const int bm = blockIdx.y << 7, bn = blockIdx.x << 6;
    const int wm = (w & 1) << 6, wn = (w >> 1) << 5;
    const int sr = lane >> 2, sc = (lane & 3) << 3;
    const f32x4 zero = {0.f, 0.f, 0.f, 0.f};
    f32x4 acc[4][2];
#pragma unroll
    for (int i = 0; i < 4; ++i)
#pragma unroll
        for (int j = 0; j < 2; ++j) acc[i][j] = zero;

    {
#pragma unroll
        for (int i = 0; i < 2; ++i) {
            const int r0 = w * 32 + i * 16;
            cp16(A + (size_t)(bm + r0 + sr) * 1024 + sc, &As[0][r0][0]);
        }
        cp16(Bt + (size_t)(bn + w * 16 + sr) * 1024 + sc, &Bs[0][w * 16][0]);
    }

    for (int kc = 0; kc < 32; ++kc) {
        const int cur = kc & 1, nxt = cur ^ 1;
        __syncthreads();
        if (kc + 1 < 32) {
            const int k1 = (kc + 1) * 32;
#pragma unroll
            for (int i = 0; i < 2; ++i) {
                const int r0 = w * 32 + i * 16;
                cp16(A + (size_t)(bm + r0 + sr) * 1024 + k1 + sc, &As[nxt][r0][0]);
            }
            cp16(Bt + (size_t)(bn + w * 16 + sr) * 1024 + k1 + sc, &Bs[nxt][w * 16][0]);
        }
        bf16x8 af[4], bfr[2];
#pragma unroll
        for (int i = 0; i < 4; ++i) af[i] = *(const bf16x8*)&As[cur][wm + i * 16 + col][quad * 8];
#pragma unroll
        for (int j = 0; j < 2; ++j) bfr[j] = *(const bf16x8*)&Bs[cur][wn + j * 16 + col][quad * 8];
#pragma unroll
        for (int i = 0; i < 4; ++i)
#pragma unroll
            for (int j = 0; j < 2; ++j)
                acc[i][j] = __builtin_amdgcn_mfma_f32_16x16x32_bf16(af[i], bfr[j], acc[i][j], 0, 0, 0);
    }
#pragma unroll
    for (int i = 0; i < 4; ++i)
#pragma unroll
        for (int j = 0; j < 2; ++j)
#pragma unroll
            for (int r = 0; r < 4; ++r)
                C[(size_t)(bm + wm + i * 16 + quad * 4 + r) * 1024 + bn + wn + j * 16 + col] =
                    acc[i][j][r];
}

// ---------------------------------------------------------------------------
// MFMA flash attention v9 (round-5 version, verbatim — best measured 87 us):
//  * cperm Vt single-buffered [64][136] (pad -> 4-bank row rotation),
//    Ks dbuf XOR-swizzled; LDS 50176 B.
//  * K=32 PV (40 full-rate MFMAs), ks-outer S, setprio around MFMA bursts.
//  * Two cheap barriers/chunk; K prefetch via cp16 stays in flight across
//    the compute phase. No cross-block communication (r4/r6 lessons).
// ---------------------------------------------------------------------------
__global__ __launch_bounds__(256) void attn_mfma(
    const u16* __restrict__ QKV, u16* __restrict__ AO)
{
    __shared__ u16 Ks[2][128][64];   // [key][dim], unpadded, XOR-swizzled 16B blocks
    __shared__ u16 Vt[64][136];      // [dim][cperm(key)] single-buffered + 8-u16 pad
    const int bid = blockIdx.x;
    int h, qt;
    if (bid < 256) { h = 8 + (bid & 7); qt = bid >> 3; }           // diff: 32 chunks
    else { int i = bid - 256; h = i & 7; qt = 31 - (i >> 3); }     // causal desc qt
    const bool causal = (h < NAR);
    const int tid = threadIdx.x;
    const int w = tid >> 6, lane = tid & 63;
    const int col = lane & 15, quad = lane >> 4;
    const int qb = qt * 128;
    const int qr0 = qb + w * 32 + col;
    const int qr1 = qr0 + 16;
    // column-permuted position of key a=2*lane (a's pair b=a+1 sits at cva+1)
    const int cva = ((lane >> 1) & 3) * 32 + (lane >> 3) * 4 + (lane & 1) * 2;

    // hoisted Q B-frags (rope'd, pre-scaled by 0.125*log2e in gemm_qkv)
    bf16x8 qf[2][2];
#pragma unroll
    for (int s = 0; s < 2; ++s)
#pragma unroll
        for (int ks = 0; ks < 2; ++ks)
            qf[s][ks] = *(const bf16x8*)(QKV + (size_t)(qr0 + s * 16) * QKVS +
                                         h * DHEAD + ks * 32 + quad * 8);

    bf16x8 ones8;
#pragma unroll
    for (int i = 0; i < 8; ++i) ones8[i] = (short)0x3F80;

    const f32x4 zero = {0.f, 0.f, 0.f, 0.f};
    f32x4 O[2][5];  // [set][nd] O^T tiles (d = nd*16+quad*4+r, q = col); nd=4 = l
#pragma unroll
    for (int s = 0; s < 2; ++s)
#pragma unroll
        for (int nd = 0; nd < 5; ++nd) O[s][nd] = zero;

    const int nch = causal ? (qt + 1) : (LSEQ / 128);
    const int krow = lane >> 3;
    const int kcb = (lane & 7) ^ krow;
    const u16* kbase = QKV + (size_t)krow * QKVS + 1024 + h * DHEAD + kcb * 8;
    const u16* vbase = QKV + (size_t)(lane * 2) * QKVS + 2048 + h * DHEAD + w * 16;

    u32x4 vA0, vA1, vB0, vB1;   // pending V(ch) regs for end-of-iter Vt write
    bf16x8 pf8[2][4];           // P(ch) frags: pf8[s][tp] = keys 32tp..32tp+31 (permuted)

#define VT_WRITE()                                                                                 \
    _Pragma("unroll")                                                                              \
    for (int j = 0; j < 4; ++j) {                                                                  \
        *(u32*)&Vt[w * 16 + 2 * j][cva]         = __builtin_amdgcn_perm(vB0[j], vA0[j], 0x05040100u); \
        *(u32*)&Vt[w * 16 + 2 * j + 1][cva]     = __builtin_amdgcn_perm(vB0[j], vA0[j], 0x07060302u); \
        *(u32*)&Vt[w * 16 + 8 + 2 * j][cva]     = __builtin_amdgcn_perm(vB1[j], vA1[j], 0x05040100u); \
        *(u32*)&Vt[w * 16 + 8 + 2 * j + 1][cva] = __builtin_amdgcn_perm(vB1[j], vA1[j], 0x07060302u); \
    }

// PV burst over Vt at K=32: tp-outer, l-row folded in -> acc reuse distance 10.
#define PV_STEP()                                                                                  \
    {                                                                                              \
        __builtin_amdgcn_s_setprio(1);                                                             \
        _Pragma("unroll")                                                                          \
        for (int tp = 0; tp < 4; ++tp) {                                                           \
            bf16x8 vv[4];                                                                          \
            _Pragma("unroll")                                                                      \
            for (int nd = 0; nd < 4; ++nd)                                                         \
                vv[nd] = *(const bf16x8*)&Vt[nd * 16 + col][quad * 32 + tp * 8];                   \
            _Pragma("unroll")                                                                      \
            for (int nd = 0; nd < 4; ++nd) {                                                       \
                O[0][nd] = __builtin_amdgcn_mfma_f32_16x16x32_bf16(vv[nd], pf8[0][tp], O[0][nd], 0, 0, 0); \
                O[1][nd] = __builtin_amdgcn_mfma_f32_16x16x32_bf16(vv[nd], pf8[1][tp], O[1][nd], 0, 0, 0); \
            }                                                                                      \
            O[0][4] = __builtin_amdgcn_mfma_f32_16x16x32_bf16(ones8, pf8[0][tp], O[0][4], 0, 0, 0); \
            O[1][4] = __builtin_amdgcn_mfma_f32_16x16x32_bf16(ones8, pf8[1][tp], O[1][4], 0, 0, 0); \
        }                                                                                          \
        __builtin_amdgcn_s_setprio(0);                                                             \
    }

// S(CH) + exp -> pf8. ks-outer: st[s][jj] reuse distance 8.
#define S_STEP(KBUF, CH)                                                                           \
    {                                                                                              \
        const bool mask = causal && ((CH) == qt);                                                  \
        _Pragma("unroll")                                                                          \
        for (int hf = 0; hf < 2; ++hf) {                                                           \
            f32x4 st[2][4];                                                                        \
            _Pragma("unroll")                                                                      \
            for (int s = 0; s < 2; ++s)                                                            \
                _Pragma("unroll")                                                                  \
                for (int jj = 0; jj < 4; ++jj) st[s][jj] = zero;                                   \
            __builtin_amdgcn_s_setprio(1);                                                         \
            _Pragma("unroll")                                                                      \
            for (int ks = 0; ks < 2; ++ks)                                                         \
                _Pragma("unroll")                                                                  \
                for (int jj = 0; jj < 4; ++jj) {                                                   \
                    bf16x8 kf = *(const bf16x8*)&Ks[KBUF][(hf * 4 + jj) * 16 + col]                \
                                                         [((ks * 4 + quad) ^ (col & 7)) * 8];      \
                    st[0][jj] = __builtin_amdgcn_mfma_f32_16x16x32_bf16(kf, qf[0][ks], st[0][jj], 0, 0, 0); \
                    st[1][jj] = __builtin_amdgcn_mfma_f32_16x16x32_bf16(kf, qf[1][ks], st[1][jj], 0, 0, 0); \
                }                                                                                  \
            __builtin_amdgcn_s_setprio(0);                                                         \
            if (mask) {                                                                            \
                _Pragma("unroll")                                                                  \
                for (int jj = 0; jj < 4; ++jj) {                                                   \
                    const int kk = (CH) * 128 + (hf * 4 + jj) * 16 + quad * 4;                     \
                    _Pragma("unroll")                                                              \
                    for (int r = 0; r < 4; ++r) {                                                  \
                        if (kk + r > qr0) st[0][jj][r] = -1e30f;                                   \
                        if (kk + r > qr1) st[1][jj][r] = -1e30f;                                   \
                    }                                                                              \
                }                                                                                  \
            }                                                                                      \
            _Pragma("unroll")                                                                      \
            for (int s = 0; s < 2; ++s)                                                            \
                _Pragma("unroll")                                                                  \
                for (int jj = 0; jj < 4; ++jj) {                                                   \
                    u32 plo = packtr(__builtin_amdgcn_exp2f(st[s][jj][0]),                         \
                                     __builtin_amdgcn_exp2f(st[s][jj][1]));                        \
                    u32 phi = packtr(__builtin_amdgcn_exp2f(st[s][jj][2]),                         \
                                     __builtin_amdgcn_exp2f(st[s][jj][3]));                        \
                    u32* p = (u32*)&pf8[s][0] + (hf * 4 + jj) * 2;                                 \
                    p[0] = plo; p[1] = phi;                                                        \
                }                                                                                  \
        }                                                                                          \
    }

    // ---- prologue: stage chunk 0 ----
#pragma unroll
    for (int i = 0; i < 4; ++i)
        cp16(kbase + (size_t)((i * 4 + w) * 8) * QKVS, &Ks[0][(i * 4 + w) * 8][0]);
    vA0 = *(u32x4*)(vbase);
    vA1 = *(u32x4*)(vbase + 8);
    vB0 = *(u32x4*)(vbase + QKVS);
    vB1 = *(u32x4*)(vbase + QKVS + 8);
    __syncthreads();  // K(0) in LDS, V(0) in regs
    VT_WRITE();       // Vt <- V(0); visibility via barrier_a of iter 1 (or tail)
    if (nch > 1) {    // prefetch K(1); drained at barrier_a of iter 1
#pragma unroll
        for (int i = 0; i < 4; ++i)
            cp16(kbase + (size_t)(128 + (i * 4 + w) * 8) * QKVS, &Ks[1][(i * 4 + w) * 8][0]);
    }
    // S(0) + exp -> pf8
    S_STEP(0, 0);

    // ---- main loop ----
    for (int ch = 1; ch < nch; ++ch) {
        const int cur = ch & 1;
        __syncthreads();  // barrier_a: Ks[cur]=K(ch) drained; Vt=V(ch-1) visible
        if (ch + 1 < nch) {  // prefetch K(ch+1) into the buffer S(ch) is NOT reading
            const size_t c1 = (size_t)(ch + 1) * 128;
#pragma unroll
            for (int i = 0; i < 4; ++i)
                cp16(kbase + (c1 + (i * 4 + w) * 8) * QKVS, &Ks[cur ^ 1][(i * 4 + w) * 8][0]);
        }
        {   // V(ch) regs for end-of-iter Vt write
            const u16* vp = vbase + (size_t)ch * 128 * QKVS;
            vA0 = *(u32x4*)(vp);
            vA1 = *(u32x4*)(vp + 8);
            vB0 = *(u32x4*)(vp + QKVS);
            vB1 = *(u32x4*)(vp + QKVS + 8);
        }
        PV_STEP();        // P(ch-1) x V(ch-1)
        S_STEP(cur, ch);  // -> pf8 = P(ch)
        __syncthreads();  // barrier_b: all PV reads done; loads above drained
        VT_WRITE();       // Vt <- V(ch)
    }

    // ---- tail: PV(nch-1) ----
    __syncthreads();  // Vt = V(nch-1) visible (prologue write if nch==1)
    PV_STEP();

    // epilogue: l already in this lane (col=q); O^T rows d = nd*16+quad*4+r
#pragma unroll
    for (int s = 0; s < 2; ++s) {
        const float inv = 1.f / O[s][4][0];
        const int qrow = qr0 + s * 16;
#pragma unroll
        for (int nd = 0; nd < 4; ++nd) {
            ushort4 ov;
            ov.x = f2bf(O[s][nd][0] * inv);
            ov.y = f2bf(O[s][nd][1] * inv);
            ov.z = f2bf(O[s][nd][2] * inv);
            ov.w = f2bf(O[s][nd][3] * inv);
            *(ushort4*)(AO + (size_t)qrow * 1024 + h * DHEAD + nd * 16 + quad * 4) = ov;
        }
    }
#undef VT_WRITE
#undef PV_STEP
#undef S_STEP
}

// ---------------------------------------------------------------------------
extern "C" void kernel_launch(void* const* d_in, const int* in_sizes, int n_in,
                              void* d_out, int out_size, void* d_ws, size_t ws_size,
                              hipStream_t stream)
{
    const float* X  = (const float*)d_in[0];
    const float* Wq = (const float*)d_in[1];
    const float* Wk = (const float*)d_in[2];
    const float* Wv = (const float*)d_in[3];
    const float* Wo = (const float*)d_in[4];
    float* out = (float*)d_out;

    // ws (u16 units), liveness overlays:
    //   [0 .. 4M):   Wqkvt [3072][1024] (dead after gemm_qkv) -> AOb [4096][1024]
    //   [4M .. 16M): QKV [4096][3072] (dead after attn) -> Wot [1024][1024]
    // d_out: Xb (bf16 X, 8 MB) during xcast..gemm_qkv; final out after gemm_out.
    u16* Wt  = (u16*)d_ws;
    u16* AOb = (u16*)d_ws;
    u16* QKV = (u16*)d_ws + (size_t)4 * 1024 * 1024;
    u16* Wot = QKV;
    u16* Xb  = (u16*)out;

    xcast<<<2048, 256, 0, stream>>>(X, Xb);
    transp_cvt3<<<dim3(16, 16, 3), 256, 0, stream>>>(Wq, Wk, Wv, Wt);
    gemm_qkv<<<dim3(24, 32), 256, 0, stream>>>(Xb, Wt, QKV);  // rope fused in epilogue
    attn_mfma<<<512, 256, 0, stream>>>(QKV, AOb);
    transp_cvt<<<dim3(16, 16), 256, 0, stream>>>(Wo, Wot);    // QKV dead now
    gemm_out<<<dim3(16, 32), 256, 0, stream>>>(AOb, Wot, out); // overwrites Xb
}